// Round 15
// baseline (226.904 us; speedup 1.0000x reference)
//
#include <hip/hip_runtime.h>
#include <hip/hip_bf16.h>

#define NEG_SLOPE 0.2f
#define BN_EPS 1e-5f

#define NBLK 256
#define COARSE_SHIFT 9
#define COARSE_NPB 512

typedef __attribute__((ext_vector_type(8))) short s8v;   // 8 bf16 (4 VGPRs)
typedef __attribute__((ext_vector_type(4))) float f4v;   // 4 fp32 acc

__device__ __forceinline__ float wred_sum(float v) {
    #pragma unroll
    for (int m = 32; m > 0; m >>= 1) v += __shfl_xor(v, m);
    return v;
}
__device__ __forceinline__ float wred_max(float v) {
    #pragma unroll
    for (int m = 32; m > 0; m >>= 1) v = fmaxf(v, __shfl_xor(v, m));
    return v;
}
__device__ __forceinline__ int wred_isum(int v) {
    #pragma unroll
    for (int m = 32; m > 0; m >>= 1) v += __shfl_xor(v, m);
    return v;
}
__device__ __forceinline__ float xor16_sum(float v) {
    #pragma unroll
    for (int m = 1; m < 16; m <<= 1) v += __shfl_xor(v, m);
    return v;
}

__device__ __forceinline__ unsigned pack_bf16(float a, float b) {
    __hip_bfloat162 t;
    t.x = __float2bfloat16(a);
    t.y = __float2bfloat16(b);
    return *(unsigned*)&t;
}
__device__ __forceinline__ float2 unpack_bf16(unsigned u) {
    __hip_bfloat162 t = *(__hip_bfloat162*)&u;
    return {__bfloat162float(t.x), __bfloat162float(t.y)};
}
__device__ __forceinline__ short bf16s(float f) {
    __hip_bfloat16 h = __float2bfloat16(f);
    return *(short*)&h;
}

__device__ __forceinline__ unsigned enc_ord(float f) {
    unsigned u = __float_as_uint(f);
    return (u & 0x80000000u) ? ~u : (u | 0x80000000u);
}
__device__ __forceinline__ float dec_ord(unsigned e) {
    unsigned u = (e & 0x80000000u) ? (e ^ 0x80000000u) : ~e;
    return __uint_as_float(u);
}

// ================= K1: gemm1 (MFMA) blocks [0,nGemmB) ∪ part_hist blocks [nGemmB, nGemmB+NBLK) =================
__global__ __launch_bounds__(256) void k1_gemm1_hist(const float* __restrict__ x,
                                                     const float* __restrict__ W,
                                                     const float* __restrict__ a1s,
                                                     const float* __restrict__ a1d,
                                                     unsigned* __restrict__ h1b,
                                                     float* __restrict__ als,
                                                     float* __restrict__ ald, int Nn, int nGemmB,
                                                     const int* __restrict__ ei, int E, int Et,
                                                     int chunk, int* __restrict__ hist, int nCoarse,
                                                     unsigned* __restrict__ gmax) {
    __shared__ __align__(16) char smem[33792];   // gemm: fragtab/lout; hist: h[128]
    int t = threadIdx.x;

    if (blockIdx.x >= nGemmB) {
        // ---------------- part_hist ----------------
        int* h = (int*)smem;
        int b = blockIdx.x - nGemmB;
        if (b == 0 && t < 4) gmax[t] = 0u;   // encoded 0 < all reals
        if (t < 128) h[t] = 0;
        __syncthreads();
        int beg = b * chunk, end = min(beg + chunk, Et);
        for (int idx = beg + t; idx < end; idx += 256) {
            int d = (idx < E) ? ei[E + idx] : (idx - E);
            atomicAdd(&h[d >> COARSE_SHIFT], 1);
        }
        __syncthreads();
        if (t < nCoarse) hist[t * NBLK + b] = h[t];
        return;
    }

    // ---------------- gemm1 via bf16 MFMA (16x16x32) + fused al1 ----------------
    short* fragtab = (short*)smem;
    float* lout    = (float*)smem;
    int br = blockIdx.x * 64;

    #pragma unroll
    for (int i = 0; i < 8; ++i) {
        int s   = t + 256 * i;
        int grp = s >> 6;
        int ls  = s & 63;
        int ct = grp >> 2, kc = grp & 3;
        int nn = ls & 15, quad = ls >> 4;
        int kb = kc * 32 + quad * 8;
        int cc = ct * 16 + nn;
        #pragma unroll
        for (int j = 0; j < 8; ++j)
            fragtab[s * 8 + j] = bf16s(W[(size_t)(kb + j) * 128 + cc]);
    }
    __syncthreads();

    int w    = t >> 6;
    int lane = t & 63;
    int nn   = lane & 15;
    int quad = lane >> 4;
    int rowbase = br + w * 16;
    int arow = min(rowbase + nn, Nn - 1);
    const float* xr = x + (size_t)arow * 128;

    f4v acc[8];
    #pragma unroll
    for (int ct = 0; ct < 8; ++ct) acc[ct] = (f4v){0.f, 0.f, 0.f, 0.f};

    #pragma unroll
    for (int kc = 0; kc < 4; ++kc) {
        float4 v0 = *(const float4*)(xr + kc * 32 + quad * 8);
        float4 v1 = *(const float4*)(xr + kc * 32 + quad * 8 + 4);
        union { s8v s; uint4 u; } A;
        A.u.x = pack_bf16(v0.x, v0.y); A.u.y = pack_bf16(v0.z, v0.w);
        A.u.z = pack_bf16(v1.x, v1.y); A.u.w = pack_bf16(v1.z, v1.w);
        #pragma unroll
        for (int ct = 0; ct < 8; ++ct) {
            s8v B = *(s8v*)(fragtab + (size_t)((ct * 4 + kc) * 64 + lane) * 8);
            acc[ct] = __builtin_amdgcn_mfma_f32_16x16x32_bf16(A.s, B, acc[ct], 0, 0, 0);
        }
    }

    float s_c[8], d_c[8];
    #pragma unroll
    for (int ct = 0; ct < 8; ++ct) {
        s_c[ct] = a1s[ct * 16 + nn];
        d_c[ct] = a1d[ct * 16 + nn];
    }
    #pragma unroll
    for (int reg = 0; reg < 4; ++reg) {
        float ps0 = 0.f, pd0 = 0.f, ps1 = 0.f, pd1 = 0.f;
        #pragma unroll
        for (int ct = 0; ct < 4; ++ct) { ps0 += acc[ct][reg] * s_c[ct]; pd0 += acc[ct][reg] * d_c[ct]; }
        #pragma unroll
        for (int ct = 4; ct < 8; ++ct) { ps1 += acc[ct][reg] * s_c[ct]; pd1 += acc[ct][reg] * d_c[ct]; }
        ps0 = xor16_sum(ps0); pd0 = xor16_sum(pd0);
        ps1 = xor16_sum(ps1); pd1 = xor16_sum(pd1);
        int r = rowbase + quad * 4 + reg;
        if (nn == 0 && r < Nn) {
            als[(size_t)r * 2]     = ps0;
            als[(size_t)r * 2 + 1] = ps1;
            ald[(size_t)r * 2]     = pd0;
            ald[(size_t)r * 2 + 1] = pd1;
        }
    }

    __syncthreads();
    #pragma unroll
    for (int ct = 0; ct < 8; ++ct)
        #pragma unroll
        for (int reg = 0; reg < 4; ++reg)
            lout[w * 2112 + (quad * 4 + reg) * 132 + ct * 16 + nn] = acc[ct][reg];
    int row_l = lane >> 2;
    int ch    = lane & 3;
    int r = rowbase + row_l;
    if (r < Nn) {
        const float* src = lout + w * 2112 + row_l * 132 + ch * 32;
        #pragma unroll
        for (int i = 0; i < 4; ++i) {
            uint4 pk = {pack_bf16(src[8 * i + 0], src[8 * i + 1]),
                        pack_bf16(src[8 * i + 2], src[8 * i + 3]),
                        pack_bf16(src[8 * i + 4], src[8 * i + 5]),
                        pack_bf16(src[8 * i + 6], src[8 * i + 7])};
            *(uint4*)(h1b + (size_t)r * 64 + ch * 16 + i * 4) = pk;
        }
    }
}

// ================= K2: csr_mid (block 0, 4 waves) ∪ almax<2> (blocks 1..64) =================
__global__ __launch_bounds__(256) void k2_mid_almax(int* __restrict__ hist,
                                                    int* __restrict__ cbase, int nCoarse,
                                                    const float* __restrict__ als,
                                                    unsigned* __restrict__ gmax, int Nn,
                                                    const float* __restrict__ b1,
                                                    const float* __restrict__ g1,
                                                    const float* __restrict__ be1,
                                                    const float* __restrict__ mn1,
                                                    const float* __restrict__ vr1,
                                                    float* __restrict__ bnscale,
                                                    float* __restrict__ bnshift) {
    __shared__ int s_ct[128];
    __shared__ int s_sc[128];
    __shared__ int s_cb[129];
    __shared__ float red[4][2];
    int t = threadIdx.x;

    if (blockIdx.x == 0) {
        // ---- csr_mid with 4 waves ----
        int wv = t >> 6, ln = t & 63;
        if (t < 128) s_ct[t] = 0;
        __syncthreads();
        for (int c = wv; c < nCoarse; c += 4) {
            int idx = c * NBLK + 4 * ln;
            int4 v = *(int4*)&hist[idx];
            int s = wred_isum(v.x + v.y + v.z + v.w);
            if (ln == 0) s_ct[c] = s;
        }
        __syncthreads();
        int v0 = 0;
        if (t < 128) { v0 = s_ct[t]; s_sc[t] = v0; }
        __syncthreads();
        for (int off = 1; off < 128; off <<= 1) {
            int u = (t >= off && t < 128) ? s_sc[t - off] : 0;
            __syncthreads();
            if (t < 128) s_sc[t] += u;
            __syncthreads();
        }
        if (t < 128) s_cb[t] = s_sc[t] - v0;
        if (t == 127) s_cb[128] = s_sc[127];
        __syncthreads();
        if (t <= nCoarse) cbase[t] = s_cb[t];
        for (int c = wv; c < nCoarse; c += 4) {
            int base = s_cb[c];
            int idx = c * NBLK + 4 * ln;
            int4 v = *(int4*)&hist[idx];
            int sl = v.x + v.y + v.z + v.w;
            int inc = sl;
            #pragma unroll
            for (int off = 1; off < 64; off <<= 1) {
                int u = __shfl_up(inc, off);
                if (ln >= off) inc += u;
            }
            int exc = inc - sl + base;
            int4 o;
            o.x = exc;
            o.y = exc + v.x;
            o.z = exc + v.x + v.y;
            o.w = exc + v.x + v.y + v.z;
            *(int4*)&hist[idx] = o;
        }
        return;
    }

    // ---- almax<2> over als[N][2] (blocks 1..64) ----
    int vb = blockIdx.x - 1;
    if (bnscale && vb == 0 && t < 128) {
        float sc = rsqrtf(vr1[t] + BN_EPS) * g1[t];
        bnscale[t] = sc;
        bnshift[t] = be1[t] + (b1[t] - mn1[t]) * sc;
    }
    float m0 = -1e30f, m1 = -1e30f;
    for (int n = vb * 256 + t; n < Nn; n += 64 * 256) {
        m0 = fmaxf(m0, als[n * 2]);
        m1 = fmaxf(m1, als[n * 2 + 1]);
    }
    m0 = wred_max(m0);
    m1 = wred_max(m1);
    int wid = t >> 6;
    if ((t & 63) == 0) { red[wid][0] = m0; red[wid][1] = m1; }
    __syncthreads();
    if (t == 0) {
        float a = fmaxf(fmaxf(red[0][0], red[1][0]), fmaxf(red[2][0], red[3][0]));
        float b = fmaxf(fmaxf(red[0][1], red[1][1]), fmaxf(red[2][1], red[3][1]));
        atomicMax(&gmax[0], enc_ord(a));
        atomicMax(&gmax[1], enc_ord(b));
    }
}

__global__ __launch_bounds__(256) void part_scatter(const int* __restrict__ ei, int E, int Et,
                                                    int chunk, const int* __restrict__ hist,
                                                    unsigned* __restrict__ staged, int nCoarse) {
    __shared__ int cur[128];
    int b = blockIdx.x, t = threadIdx.x;
    if (t < nCoarse) cur[t] = hist[t * NBLK + b];
    __syncthreads();
    int beg = b * chunk, end = min(beg + chunk, Et);
    for (int idx = beg + t; idx < end; idx += 256) {
        int s, d;
        if (idx < E) { s = ei[idx]; d = ei[E + idx]; }
        else         { s = idx - E; d = idx - E; }
        int c = d >> COARSE_SHIFT;
        int pos = atomicAdd(&cur[c], 1);
        staged[pos] = ((unsigned)s << COARSE_SHIFT) | (unsigned)(d & (COARSE_NPB - 1));
    }
}

__global__ __launch_bounds__(512) void fine_place(const unsigned* __restrict__ staged,
                                                  const int* __restrict__ cbase,
                                                  int* __restrict__ offs,
                                                  int* __restrict__ csr, int Nn, int nCoarse) {
    __shared__ int hcnt[COARSE_NPB];
    __shared__ int scn[COARSE_NPB];
    int b = blockIdx.x, t = threadIdx.x;
    int node0 = b << COARSE_SHIFT;
    int nloc = min(COARSE_NPB, Nn - node0);
    hcnt[t] = 0;
    __syncthreads();
    int ebeg = cbase[b], eend = cbase[b + 1];
    for (int p = ebeg + t; p < eend; p += 512) {
        atomicAdd(&hcnt[staged[p] & (COARSE_NPB - 1)], 1);
    }
    __syncthreads();
    int val = hcnt[t];
    scn[t] = val;
    __syncthreads();
    for (int off = 1; off < COARSE_NPB; off <<= 1) {
        int u = (t >= off) ? scn[t - off] : 0;
        __syncthreads();
        scn[t] += u;
        __syncthreads();
    }
    int exc = ebeg + scn[t] - val;
    if (t < nloc) offs[node0 + t] = exc;
    if (b == nCoarse - 1 && t == 0) offs[Nn] = eend;
    hcnt[t] = exc;
    __syncthreads();
    for (int p = ebeg + t; p < eend; p += 512) {
        unsigned v = staged[p];
        int pos = atomicAdd(&hcnt[v & (COARSE_NPB - 1)], 1);
        csr[pos] = (int)(v >> COARSE_SHIFT);
    }
}

// ---- almax<1> for layer 2 ----
__global__ __launch_bounds__(256) void almax1_kernel(const float* __restrict__ als,
                                                     unsigned* __restrict__ gmax, int Nn) {
    __shared__ float red[4];
    int t = threadIdx.x;
    float m = -1e30f;
    for (int n = blockIdx.x * 256 + t; n < Nn; n += gridDim.x * 256)
        m = fmaxf(m, als[n]);
    m = wred_max(m);
    int wid = t >> 6;
    if ((t & 63) == 0) red[wid] = m;
    __syncthreads();
    if (t == 0) {
        float mm = fmaxf(fmaxf(red[0], red[1]), fmaxf(red[2], red[3]));
        atomicMax(&gmax[2], enc_ord(mm));
    }
}

// ---------------- softagg1: 4 nodes/wave, 16 lanes/node, lane owns 8 cols ----------------
__global__ __launch_bounds__(256) void softagg1_kernel(const int* __restrict__ offs, const int* __restrict__ csr,
                            const unsigned* __restrict__ h1b,
                            const float* __restrict__ als, const float* __restrict__ ald,
                            const unsigned* __restrict__ gmax,
                            const float* __restrict__ bnscale, const float* __restrict__ bnshift,
                            unsigned* __restrict__ hbnb, int Nn) {
    __shared__ int   sh_s[4][4][16];
    __shared__ float sh_e[4][4][2][16];
    int wid = threadIdx.x >> 6, lane = threadIdx.x & 63;
    int g = lane >> 4;
    int l = lane & 15;
    int head = l >> 3;
    int n = blockIdx.x * 16 + wid * 4 + g;
    if (n >= Nn) return;
    int b = offs[n], e = offs[n + 1];
    float2 aldn = *(const float2*)(ald + (size_t)n * 2);
    float bd0 = dec_ord(gmax[0]) + aldn.x; bd0 = (bd0 > 0.f) ? bd0 : NEG_SLOPE * bd0;
    float bd1 = dec_ord(gmax[1]) + aldn.y; bd1 = (bd1 > 0.f) ? bd1 : NEG_SLOPE * bd1;

    float acc[8];
    #pragma unroll
    for (int j = 0; j < 8; ++j) acc[j] = 0.f;
    float den0 = 0.f, den1 = 0.f;

    for (int base = b; base < e; base += 16) {
        int cnt = min(16, e - base);
        int   s1 = 0;
        float e0r = 0.f, e1r = 0.f;
        if (l < cnt) {
            s1 = csr[base + l];
            float2 as = *(const float2*)(als + (size_t)s1 * 2);
            float l0 = as.x + aldn.x; l0 = (l0 > 0.f) ? l0 : NEG_SLOPE * l0;
            float l1 = as.y + aldn.y; l1 = (l1 > 0.f) ? l1 : NEG_SLOPE * l1;
            e0r = __expf(l0 - bd0);
            e1r = __expf(l1 - bd1);
            den0 += e0r; den1 += e1r;
        }
        sh_s[wid][g][l]    = s1;
        sh_e[wid][g][0][l] = e0r;
        sh_e[wid][g][1][l] = e1r;
        int i = 0;
        for (; i + 1 < cnt; i += 2) {
            int   sA  = sh_s[wid][g][i];
            int   sB  = sh_s[wid][g][i + 1];
            float evA = sh_e[wid][g][head][i];
            float evB = sh_e[wid][g][head][i + 1];
            uint4 vA = *(const uint4*)(h1b + (size_t)sA * 64 + 4 * l);
            uint4 vB = *(const uint4*)(h1b + (size_t)sB * 64 + 4 * l);
            float2 f;
            f = unpack_bf16(vA.x); acc[0] += f.x * evA; acc[1] += f.y * evA;
            f = unpack_bf16(vA.y); acc[2] += f.x * evA; acc[3] += f.y * evA;
            f = unpack_bf16(vA.z); acc[4] += f.x * evA; acc[5] += f.y * evA;
            f = unpack_bf16(vA.w); acc[6] += f.x * evA; acc[7] += f.y * evA;
            f = unpack_bf16(vB.x); acc[0] += f.x * evB; acc[1] += f.y * evB;
            f = unpack_bf16(vB.y); acc[2] += f.x * evB; acc[3] += f.y * evB;
            f = unpack_bf16(vB.z); acc[4] += f.x * evB; acc[5] += f.y * evB;
            f = unpack_bf16(vB.w); acc[6] += f.x * evB; acc[7] += f.y * evB;
        }
        if (i < cnt) {
            int   s  = sh_s[wid][g][i];
            float ev = sh_e[wid][g][head][i];
            uint4 v = *(const uint4*)(h1b + (size_t)s * 64 + 4 * l);
            float2 f;
            f = unpack_bf16(v.x); acc[0] += f.x * ev; acc[1] += f.y * ev;
            f = unpack_bf16(v.y); acc[2] += f.x * ev; acc[3] += f.y * ev;
            f = unpack_bf16(v.z); acc[4] += f.x * ev; acc[5] += f.y * ev;
            f = unpack_bf16(v.w); acc[6] += f.x * ev; acc[7] += f.y * ev;
        }
    }
    #pragma unroll
    for (int m = 1; m < 16; m <<= 1) {
        den0 += __shfl_xor(den0, m);
        den1 += __shfl_xor(den1, m);
    }
    float inv = 1.f / ((head ? den1 : den0) + 1e-16f);
    int c = 8 * l;
    float4 sa = *(const float4*)(bnscale + c), sb = *(const float4*)(bnscale + c + 4);
    float4 ha = *(const float4*)(bnshift + c), hb = *(const float4*)(bnshift + c + 4);
    float o0 = fmaxf(acc[0] * inv * sa.x + ha.x, 0.f);
    float o1 = fmaxf(acc[1] * inv * sa.y + ha.y, 0.f);
    float o2 = fmaxf(acc[2] * inv * sa.z + ha.z, 0.f);
    float o3 = fmaxf(acc[3] * inv * sa.w + ha.w, 0.f);
    float o4 = fmaxf(acc[4] * inv * sb.x + hb.x, 0.f);
    float o5 = fmaxf(acc[5] * inv * sb.y + hb.y, 0.f);
    float o6 = fmaxf(acc[6] * inv * sb.z + hb.z, 0.f);
    float o7 = fmaxf(acc[7] * inv * sb.w + hb.w, 0.f);
    uint4 pk = {pack_bf16(o0, o1), pack_bf16(o2, o3), pack_bf16(o4, o5), pack_bf16(o6, o7)};
    *(uint4*)(hbnb + (size_t)n * 64 + 4 * l) = pk;
}

// ---------------- Layer 2 GEMM (A from bf16 hbnb) + fused al2; h2b rows = 20 uints ----------------
__global__ __launch_bounds__(256) void gemm2_tiled(const unsigned* __restrict__ hbnb,
                                                   const float* __restrict__ W2,
                                                   const float* __restrict__ a2s,
                                                   const float* __restrict__ a2d,
                                                   unsigned* __restrict__ h2b,
                                                   float* __restrict__ als, float* __restrict__ ald,
                                                   int Nn) {
    __shared__ float Ast[32][132];
    __shared__ float Bs[32][68];
    int t  = threadIdx.x;
    int tx = t & 15;
    int ty = t >> 4;
    int br = blockIdx.x * 128;

    float as4[4], ad4[4];
    #pragma unroll
    for (int j = 0; j < 4; ++j) {
        int c = 4 * tx + j;
        as4[j] = (c < 40) ? a2s[c] : 0.f;
        ad4[j] = (c < 40) ? a2d[c] : 0.f;
    }

    float acc[8][4];
    #pragma unroll
    for (int i = 0; i < 8; ++i)
        #pragma unroll
        for (int j = 0; j < 4; ++j) acc[i][j] = 0.f;

    int k4   = t & 7;
    int rowA = t >> 3;

    for (int k0 = 0; k0 < 128; k0 += 32) {
        #pragma unroll
        for (int i = 0; i < 4; ++i) {
            int r  = rowA + 32 * i;
            int gr = min(br + r, Nn - 1);
            uint2 v2 = *(const uint2*)(hbnb + (size_t)gr * 64 + (k0 >> 1) + 2 * k4);
            float2 f0 = unpack_bf16(v2.x), f1 = unpack_bf16(v2.y);
            Ast[4 * k4 + 0][r] = f0.x; Ast[4 * k4 + 1][r] = f0.y;
            Ast[4 * k4 + 2][r] = f1.x; Ast[4 * k4 + 3][r] = f1.y;
        }
        #pragma unroll
        for (int i = 0; i < 2; ++i) {
            int f  = t + 256 * i;
            int kk = f >> 4, c4 = f & 15;
            float4 v = {0.f, 0.f, 0.f, 0.f};
            if (c4 < 10) v = *(const float4*)(W2 + (size_t)(k0 + kk) * 40 + 4 * c4);
            *(float4*)&Bs[kk][4 * c4] = v;
        }
        __syncthreads();
        #pragma unroll 8
        for (int kk = 0; kk < 32; ++kk) {
            float4 a0 = *(const float4*)&Ast[kk][8 * ty];
            float4 a1 = *(const float4*)&Ast[kk][8 * ty + 4];
            float4 b0 = *(const float4*)&Bs[kk][4 * tx];
            float av[8] = {a0.x, a0.y, a0.z, a0.w, a1.x, a1.y, a1.z, a1.w};
            #pragma unroll
            for (int i = 0; i < 8; ++i) {
                acc[i][0] += av[i] * b0.x; acc[i][1] += av[i] * b0.y;
                acc[i][2] += av[i] * b0.z; acc[i][3] += av[i] * b0.w;
            }
        }
        __syncthreads();
    }

    #pragma unroll
    for (int i = 0; i < 8; ++i) {
        int r = br + 8 * ty + i;
        if (r < Nn && tx < 10) {
            uint2 pk = {pack_bf16(acc[i][0], acc[i][1]), pack_bf16(acc[i][2], acc[i][3])};
            *(uint2*)(h2b + (size_t)r * 20 + 2 * tx) = pk;
        }
        float ps = acc[i][0] * as4[0] + acc[i][1] * as4[1] + acc[i][2] * as4[2] + acc[i][3] * as4[3];
        float pd = acc[i][0] * ad4[0] + acc[i][1] * ad4[1] + acc[i][2] * ad4[2] + acc[i][3] * ad4[3];
        float sS = xor16_sum(ps);
        float sD = xor16_sum(pd);
        if (tx == 0 && r < Nn) { als[r] = sS; ald[r] = sD; }
    }
}

// ---------------- softagg2: 8 nodes/wave, 8 lanes/node (stride-20 h2b) ----------------
__global__ __launch_bounds__(256) void softagg2_kernel(const int* __restrict__ offs, const int* __restrict__ csr,
                            const unsigned* __restrict__ h2b,
                            const float* __restrict__ als, const float* __restrict__ ald,
                            const unsigned* __restrict__ gmax,
                            const float* __restrict__ b2,
                            float* __restrict__ out, int Nn) {
    __shared__ int   sh_s[4][8][8];
    __shared__ float sh_ev[4][8][8];
    int wid = threadIdx.x >> 6, lane = threadIdx.x & 63;
    int g = lane >> 3;
    int l = lane & 7;
    int n = blockIdx.x * 32 + wid * 8 + g;
    if (n >= Nn) return;
    int b = offs[n], e = offs[n + 1];
    float aldn = ald[n];
    float bound = dec_ord(gmax[2]) + aldn;
    bound = (bound > 0.f) ? bound : NEG_SLOPE * bound;

    float acc[8];
    #pragma unroll
    for (int j = 0; j < 8; ++j) acc[j] = 0.f;
    float den = 0.f;

    for (int base = b; base < e; base += 8) {
        int cnt = min(8, e - base);
        int   s1 = 0;
        float evr = 0.f;
        if (l < cnt) {
            s1 = csr[base + l];
            float lv = als[s1] + aldn;
            lv = (lv > 0.f) ? lv : NEG_SLOPE * lv;
            evr = __expf(lv - bound);
            den += evr;
        }
        sh_s[wid][g][l]  = s1;
        sh_ev[wid][g][l] = evr;
        if (l < 5) {
            int i = 0;
            for (; i + 1 < cnt; i += 2) {
                int   sA  = sh_s[wid][g][i];
                int   sB  = sh_s[wid][g][i + 1];
                float evA = sh_ev[wid][g][i];
                float evB = sh_ev[wid][g][i + 1];
                uint4 vA = *(const uint4*)(h2b + (size_t)sA * 20 + 4 * l);
                uint4 vB = *(const uint4*)(h2b + (size_t)sB * 20 + 4 * l);
                float2 f;
                f = unpack_bf16(vA.x); acc[0] += f.x * evA; acc[1] += f.y * evA;
                f = unpack_bf16(vA.y); acc[2] += f.x * evA; acc[3] += f.y * evA;
                f = unpack_bf16(vA.z); acc[4] += f.x * evA; acc[5] += f.y * evA;
                f = unpack_bf16(vA.w); acc[6] += f.x * evA; acc[7] += f.y * evA;
                f = unpack_bf16(vB.x); acc[0] += f.x * evB; acc[1] += f.y * evB;
                f = unpack_bf16(vB.y); acc[2] += f.x * evB; acc[3] += f.y * evB;
                f = unpack_bf16(vB.z); acc[4] += f.x * evB; acc[5] += f.y * evB;
                f = unpack_bf16(vB.w); acc[6] += f.x * evB; acc[7] += f.y * evB;
            }
            if (i < cnt) {
                int   s  = sh_s[wid][g][i];
                float ev = sh_ev[wid][g][i];
                uint4 v = *(const uint4*)(h2b + (size_t)s * 20 + 4 * l);
                float2 f;
                f = unpack_bf16(v.x); acc[0] += f.x * ev; acc[1] += f.y * ev;
                f = unpack_bf16(v.y); acc[2] += f.x * ev; acc[3] += f.y * ev;
                f = unpack_bf16(v.z); acc[4] += f.x * ev; acc[5] += f.y * ev;
                f = unpack_bf16(v.w); acc[6] += f.x * ev; acc[7] += f.y * ev;
            }
        }
    }
    #pragma unroll
    for (int m = 1; m < 8; m <<= 1) den += __shfl_xor(den, m);
    float inv = 1.f / (den + 1e-16f);
    bool valid = (l < 5);
    float vv[8];
    float lmax = -1e30f;
    if (valid) {
        int c = 8 * l;
        #pragma unroll
        for (int j = 0; j < 8; ++j) {
            vv[j] = acc[j] * inv + b2[c + j];
            lmax = fmaxf(lmax, vv[j]);
        }
    }
    float m = lmax;
    #pragma unroll
    for (int mm = 1; mm < 8; mm <<= 1) m = fmaxf(m, __shfl_xor(m, mm));
    float es = 0.f;
    if (valid) {
        #pragma unroll
        for (int j = 0; j < 8; ++j) es += __expf(vv[j] - m);
    }
    #pragma unroll
    for (int mm = 1; mm < 8; mm <<= 1) es += __shfl_xor(es, mm);
    float lse = m + logf(es);
    if (valid) {
        float4 oa = {vv[0] - lse, vv[1] - lse, vv[2] - lse, vv[3] - lse};
        float4 ob = {vv[4] - lse, vv[5] - lse, vv[6] - lse, vv[7] - lse};
        *(float4*)(out + (size_t)n * 40 + 8 * l)     = oa;
        *(float4*)(out + (size_t)n * 40 + 8 * l + 4) = ob;
    }
}

extern "C" void kernel_launch(void* const* d_in, const int* in_sizes, int n_in,
                              void* d_out, int out_size, void* d_ws, size_t ws_size,
                              hipStream_t stream) {
    const float* x    = (const float*)d_in[0];
    const int*   ei   = (const int*)d_in[1];
    const float* W1   = (const float*)d_in[2];
    const float* a1s  = (const float*)d_in[3];
    const float* a1d  = (const float*)d_in[4];
    const float* b1   = (const float*)d_in[5];
    const float* g1   = (const float*)d_in[6];
    const float* be1  = (const float*)d_in[7];
    const float* mn1  = (const float*)d_in[8];
    const float* vr1  = (const float*)d_in[9];
    const float* W2   = (const float*)d_in[10];
    const float* a2s  = (const float*)d_in[11];
    const float* a2d  = (const float*)d_in[12];
    const float* b2   = (const float*)d_in[13];
    float* out = (float*)d_out;

    const int N  = in_sizes[0] / 128;
    const int E  = in_sizes[1] / 2;
    const int Et = E + N;
    const int nCoarse = (N + COARSE_NPB - 1) >> COARSE_SHIFT;
    const int chunk   = (Et + NBLK - 1) / NBLK;
    const int nGemmB  = (N + 63) / 64;

    char* p = (char*)d_ws;
    auto alloc = [&](size_t bytes) -> void* {
        void* r = (void*)p;
        p += (bytes + 255) & ~(size_t)255;
        return r;
    };
    int*      hist   = (int*)alloc((size_t)nCoarse * NBLK * 4);
    int*      cbase  = (int*)alloc((size_t)(nCoarse + 1) * 4);
    int*      offs   = (int*)alloc((size_t)(N + 1) * 4);
    unsigned* staged = (unsigned*)alloc((size_t)Et * 4);
    int*      csr    = (int*)alloc((size_t)Et * 4);
    unsigned* h1b    = (unsigned*)alloc((size_t)N * 64 * 4);
    float*    al1sv  = (float*)alloc((size_t)N * 2 * 4);
    float*    al1dv  = (float*)alloc((size_t)N * 2 * 4);
    unsigned* hbnb   = (unsigned*)alloc((size_t)N * 64 * 4);
    unsigned* h2b    = (unsigned*)alloc((size_t)N * 20 * 4);
    float*    al2sv  = (float*)alloc((size_t)N * 4);
    float*    al2dv  = (float*)alloc((size_t)N * 4);
    unsigned* gmax   = (unsigned*)alloc(4 * 4);
    float*    bnscale= (float*)alloc(128 * 4);
    float*    bnshift= (float*)alloc(128 * 4);
    (void)ws_size;

    // K1: gemm1 (MFMA) + part_hist in one grid (independent subsystems overlap)
    k1_gemm1_hist<<<nGemmB + NBLK, 256, 0, stream>>>(x, W1, a1s, a1d, h1b, al1sv, al1dv, N, nGemmB,
                                                     ei, E, Et, chunk, hist, nCoarse, gmax);
    // K2: csr_mid (block 0) + almax<2> (blocks 1..64)
    k2_mid_almax<<<65, 256, 0, stream>>>(hist, cbase, nCoarse, al1sv, gmax, N,
                                         b1, g1, be1, mn1, vr1, bnscale, bnshift);
    part_scatter<<<NBLK, 256, 0, stream>>>(ei, E, Et, chunk, hist, staged, nCoarse);
    fine_place<<<nCoarse, 512, 0, stream>>>(staged, cbase, offs, csr, N, nCoarse);

    softagg1_kernel<<<(N + 15) / 16, 256, 0, stream>>>(offs, csr, h1b, al1sv, al1dv, gmax,
                                                       bnscale, bnshift, hbnb, N);

    gemm2_tiled<<<(N + 127) / 128, 256, 0, stream>>>(hbnb, W2, a2s, a2d, h2b, al2sv, al2dv, N);
    almax1_kernel<<<64, 256, 0, stream>>>(al2sv, gmax, N);
    softagg2_kernel<<<(N + 31) / 32, 256, 0, stream>>>(offs, csr, h2b, al2sv, al2dv, gmax, b2, out, N);
}